// Round 7
// baseline (461.825 us; speedup 1.0000x reference)
//
#include <hip/hip_runtime.h>
#include <math.h>

#define N_TOK 32768
#define IN_DIM 1024
#define HID 256
#define NE 64

// ---------------------------------------------------------------------------
// Pre-pass: W1[256][1024] -> W1T[1024][256] (1 MB workspace) so the hot
// kernel can DMA W rows [k][h] into LDS linearly (global_load_lds needs a
// linear, non-transposed destination).
// ---------------------------------------------------------------------------
__global__ __launch_bounds__(256)
void transpose_w1(const float* __restrict__ w1, float* __restrict__ w1t)
{
    __shared__ float tile[32][33];
    const int k0 = blockIdx.x * 32;
    const int h0 = blockIdx.y * 32;
    const int j  = threadIdx.x & 31;
    const int i0 = threadIdx.x >> 5;
    #pragma unroll
    for (int r = 0; r < 4; ++r) {
        int i = i0 + r * 8;
        tile[i][j] = w1[(size_t)(h0 + i) * IN_DIM + k0 + j];
    }
    __syncthreads();
    #pragma unroll
    for (int r = 0; r < 4; ++r) {
        int i = i0 + r * 8;
        w1t[(size_t)(k0 + i) * HID + h0 + j] = tile[j][i];
    }
}

// direct global->LDS DMA, 16 B per lane (guide: the compiler never auto-emits
// this; width 4->16 alone was +67% in learn_hip m193)
__device__ __forceinline__ void gload_lds16(const float* g, float* l)
{
    __builtin_amdgcn_global_load_lds(
        (const __attribute__((address_space(1))) void*)g,
        (__attribute__((address_space(3))) void*)l,
        16, 0, 0);
}

// ---------------------------------------------------------------------------
// Round-7: relieve the per-CU LDS pipe (R2/R6 both measured VALUBusy 50-56%
// = the 1.9x-oversubscription ceiling):
//   - X-fragments: half-wave-uniform -> float2 register double-buffer from
//     global (L3-resident), NOT via LDS. Kills 2 of 4 ds_read_b128 per k.
//   - W staging: global_load_lds width-16 from W1T. Kills all ds_write
//     staging traffic + the VGPR round-trip.
//   - W-fragment reads keep the R2/R6-proven conflict-free shape: 32
//     distinct 16B slots spanning 512 B + 2-way lane broadcast.
//     (R4/R5's 64-slot/1024B-span pattern costs ~30 cyc/op - avoided.)
// New per-chunk-CU balance: LDS ~0.8x VALU -> VALU-bound.
// LDS = one 32 KB union -> up to 5 blocks/CU.
// k-order per output element unchanged -> bit-identical outputs.
// ---------------------------------------------------------------------------
union SMem {
    float Ws[32][256];   // phase A: W1T rows k0..k0+31 (linear, DMA-written)
    float Hs[32][256];   // phase B: H tile [tok][hid]
};

__global__ __launch_bounds__(128, 2)
void moe_gate(const float* __restrict__ x,  const float* __restrict__ w1t,
              const float* __restrict__ b1, const float* __restrict__ w2,
              const float* __restrict__ b2, float* __restrict__ out)
{
    __shared__ SMem sm;

    const int tid = threadIdx.x;
    const int tg  = tid >> 5;       // 0..3  -> tokens tg*8 .. tg*8+7
    const int hg  = tid & 31;       // 0..31 -> hiddens {hg*4..+3, 128+hg*4..+3}
    const int t0  = blockIdx.x * 32;

    const float* xb   = x + (size_t)(t0 + tg * 8) * IN_DIM;
    const float* wrow = &sm.Ws[0][hg * 4];   // + k*256 (+128 for high half)

    float acc[8][8];
    #pragma unroll
    for (int i = 0; i < 8; ++i)
        #pragma unroll
        for (int j = 0; j < 8; ++j) acc[i][j] = 0.f;

    // ---------------- phase A: H = relu(X @ W1T + b1) ----------------
    #pragma unroll 1
    for (int c = 0; c < 32; ++c) {
        const int k0 = c * 32;

        // DMA-stage Ws <- W1T[k0..k0+32)[0..256): 2048 16B slots, 16/thread.
        // lds dest = wave-uniform base + lane*16 (linear), src linear. ✓
        #pragma unroll
        for (int r = 0; r < 16; ++r) {
            int slot = tid + 128 * r;
            gload_lds16(w1t + (size_t)k0 * HID + slot * 4, &sm.Ws[0][0] + slot * 4);
        }

        // X init for this chunk (independent of staging; drained by barrier)
        float2 xA[8], xB[8];
        #pragma unroll
        for (int t = 0; t < 8; ++t)
            xA[t] = *(const float2*)(xb + (size_t)t * IN_DIM + k0);
        #pragma unroll
        for (int t = 0; t < 8; ++t)
            xB[t] = *(const float2*)(xb + (size_t)t * IN_DIM + k0 + 2);

        __syncthreads();   // staging + X init complete

        #pragma unroll
        for (int g = 0; g < 8; ++g) {
            const int k = g * 4;
            // k, k+1 from xA
            float4 w00 = *(const float4*)(wrow + (k + 0) * 256);
            float4 w01 = *(const float4*)(wrow + (k + 0) * 256 + 128);
            float4 w10 = *(const float4*)(wrow + (k + 1) * 256);
            float4 w11 = *(const float4*)(wrow + (k + 1) * 256 + 128);
            #pragma unroll
            for (int t = 0; t < 8; ++t) {
                acc[t][0] = fmaf(xA[t].x, w00.x, acc[t][0]);
                acc[t][1] = fmaf(xA[t].x, w00.y, acc[t][1]);
                acc[t][2] = fmaf(xA[t].x, w00.z, acc[t][2]);
                acc[t][3] = fmaf(xA[t].x, w00.w, acc[t][3]);
                acc[t][4] = fmaf(xA[t].x, w01.x, acc[t][4]);
                acc[t][5] = fmaf(xA[t].x, w01.y, acc[t][5]);
                acc[t][6] = fmaf(xA[t].x, w01.z, acc[t][6]);
                acc[t][7] = fmaf(xA[t].x, w01.w, acc[t][7]);
            }
            #pragma unroll
            for (int t = 0; t < 8; ++t) {
                acc[t][0] = fmaf(xA[t].y, w10.x, acc[t][0]);
                acc[t][1] = fmaf(xA[t].y, w10.y, acc[t][1]);
                acc[t][2] = fmaf(xA[t].y, w10.z, acc[t][2]);
                acc[t][3] = fmaf(xA[t].y, w10.w, acc[t][3]);
                acc[t][4] = fmaf(xA[t].y, w11.x, acc[t][4]);
                acc[t][5] = fmaf(xA[t].y, w11.y, acc[t][5]);
                acc[t][6] = fmaf(xA[t].y, w11.z, acc[t][6]);
                acc[t][7] = fmaf(xA[t].y, w11.w, acc[t][7]);
            }
            if (g < 7) {   // refill xA <- k0+k+4, +5
                #pragma unroll
                for (int t = 0; t < 8; ++t)
                    xA[t] = *(const float2*)(xb + (size_t)t * IN_DIM + k0 + k + 4);
            }
            // k+2, k+3 from xB
            float4 w20 = *(const float4*)(wrow + (k + 2) * 256);
            float4 w21 = *(const float4*)(wrow + (k + 2) * 256 + 128);
            float4 w30 = *(const float4*)(wrow + (k + 3) * 256);
            float4 w31 = *(const float4*)(wrow + (k + 3) * 256 + 128);
            #pragma unroll
            for (int t = 0; t < 8; ++t) {
                acc[t][0] = fmaf(xB[t].x, w20.x, acc[t][0]);
                acc[t][1] = fmaf(xB[t].x, w20.y, acc[t][1]);
                acc[t][2] = fmaf(xB[t].x, w20.z, acc[t][2]);
                acc[t][3] = fmaf(xB[t].x, w20.w, acc[t][3]);
                acc[t][4] = fmaf(xB[t].x, w21.x, acc[t][4]);
                acc[t][5] = fmaf(xB[t].x, w21.y, acc[t][5]);
                acc[t][6] = fmaf(xB[t].x, w21.z, acc[t][6]);
                acc[t][7] = fmaf(xB[t].x, w21.w, acc[t][7]);
            }
            #pragma unroll
            for (int t = 0; t < 8; ++t) {
                acc[t][0] = fmaf(xB[t].y, w30.x, acc[t][0]);
                acc[t][1] = fmaf(xB[t].y, w30.y, acc[t][1]);
                acc[t][2] = fmaf(xB[t].y, w30.z, acc[t][2]);
                acc[t][3] = fmaf(xB[t].y, w30.w, acc[t][3]);
                acc[t][4] = fmaf(xB[t].y, w31.x, acc[t][4]);
                acc[t][5] = fmaf(xB[t].y, w31.y, acc[t][5]);
                acc[t][6] = fmaf(xB[t].y, w31.z, acc[t][6]);
                acc[t][7] = fmaf(xB[t].y, w31.w, acc[t][7]);
            }
            if (g < 7) {   // refill xB <- k0+k+6, +7
                #pragma unroll
                for (int t = 0; t < 8; ++t)
                    xB[t] = *(const float2*)(xb + (size_t)t * IN_DIM + k0 + k + 6);
            }
        }
        __syncthreads();   // all reads of Ws done before next DMA overwrites
    }

    // bias + relu (j 0..3 -> h=hg*4+j, j 4..7 -> h=128+hg*4+(j-4))
    {
        float4 bb0 = *(const float4*)(b1 + hg * 4);
        float4 bb1 = *(const float4*)(b1 + 128 + hg * 4);
        float bias1[8] = {bb0.x, bb0.y, bb0.z, bb0.w, bb1.x, bb1.y, bb1.z, bb1.w};
        #pragma unroll
        for (int i = 0; i < 8; ++i)
            #pragma unroll
            for (int j = 0; j < 8; ++j)
                acc[i][j] = fmaxf(acc[i][j] + bias1[j], 0.f);
    }

    // dump H -> LDS [tok][hid] (final barrier above drained all Ws readers;
    // writes: 2 rows x 32 slots -> 2-way aliasing = free)
    #pragma unroll
    for (int i = 0; i < 8; ++i) {
        *(float4*)&sm.Hs[tg * 8 + i][hg * 4] =
            make_float4(acc[i][0], acc[i][1], acc[i][2], acc[i][3]);
        *(float4*)&sm.Hs[tg * 8 + i][128 + hg * 4] =
            make_float4(acc[i][4], acc[i][5], acc[i][6], acc[i][7]);
    }
    __syncthreads();

    // ---------------- phase B: logits + top-2 + softmax (R6-proven) --------
    const int tp = tid >> 4;   // 0..7  -> tokens tp*4 .. tp*4+3
    const int e4 = tid & 15;   // 0..15 -> experts e4*4 .. e4*4+3

    const float* hp[4] = { &sm.Hs[tp * 4 + 0][0], &sm.Hs[tp * 4 + 1][0],
                           &sm.Hs[tp * 4 + 2][0], &sm.Hs[tp * 4 + 3][0] };
    const float* w2p = w2 + (size_t)(e4 * 4) * HID;

    float acc2[4][4];
    #pragma unroll
    for (int i = 0; i < 4; ++i)
        #pragma unroll
        for (int j = 0; j < 4; ++j) acc2[i][j] = 0.f;

    #pragma unroll 2
    for (int k4 = 0; k4 < 64; ++k4) {
        const int k = k4 * 4;
        float hvv[4][4], evv[4][4];
        #pragma unroll
        for (int i = 0; i < 4; ++i)
            *(float4*)&hvv[i][0] = *(const float4*)(hp[i] + k);
        #pragma unroll
        for (int j = 0; j < 4; ++j)
            *(float4*)&evv[j][0] = *(const float4*)(w2p + (size_t)j * HID + k);
        #pragma unroll
        for (int d = 0; d < 4; ++d)
            #pragma unroll
            for (int i = 0; i < 4; ++i)
                #pragma unroll
                for (int j = 0; j < 4; ++j)
                    acc2[i][j] = fmaf(hvv[i][d], evv[j][d], acc2[i][j]);
    }

    // + b2, then per-token top-2 across the 16 e4-lanes (strict total order
    // (value desc, index asc) == jax.lax.top_k; verified rounds 4/5/6).
    float4 b2v = *(const float4*)(b2 + e4 * 4);
    #pragma unroll
    for (int i = 0; i < 4; ++i) {
        float v[4] = {acc2[i][0] + b2v.x, acc2[i][1] + b2v.y,
                      acc2[i][2] + b2v.z, acc2[i][3] + b2v.w};
        float m1 = -INFINITY, m2 = -INFINITY;
        int i1 = 0, i2 = 0;
        #pragma unroll
        for (int j = 0; j < 4; ++j) {
            int e = e4 * 4 + j;
            if (v[j] > m1)      { m2 = m1; i2 = i1; m1 = v[j]; i1 = e; }
            else if (v[j] > m2) { m2 = v[j]; i2 = e; }
        }
        #pragma unroll
        for (int off = 1; off < 16; off <<= 1) {
            float om1 = __shfl_xor(m1, off);
            int   oi1 = __shfl_xor(i1, off);
            float om2 = __shfl_xor(m2, off);
            int   oi2 = __shfl_xor(i2, off);
            bool bwin = (om1 > m1) || (om1 == m1 && oi1 < i1);
            float c1v = bwin ? om1 : m1;  int c1i = bwin ? oi1 : i1;
            float lv  = bwin ? m1  : om1; int li  = bwin ? i1  : oi1;
            float w2v = bwin ? om2 : m2;  int w2i = bwin ? oi2 : i2;
            bool s = (lv > w2v) || (lv == w2v && li < w2i);
            m1 = c1v; i1 = c1i;
            m2 = s ? lv : w2v; i2 = s ? li : w2i;
        }
        if (e4 == 0) {
            float ex  = expf(m2 - m1);          // <= 1, no overflow
            float inv = 1.f / (1.f + ex);
            int gt = t0 + tp * 4 + i;
            out[(size_t)gt * 2 + 0] = (float)i1;
            out[(size_t)gt * 2 + 1] = (float)i2;
            out[(size_t)2 * N_TOK + (size_t)gt * 2 + 0] = inv;
            out[(size_t)2 * N_TOK + (size_t)gt * 2 + 1] = ex * inv;
        }
    }
}

extern "C" void kernel_launch(void* const* d_in, const int* in_sizes, int n_in,
                              void* d_out, int out_size, void* d_ws, size_t ws_size,
                              hipStream_t stream) {
    const float* x  = (const float*)d_in[0];  // [32768,1024]
    const float* w1 = (const float*)d_in[1];  // [256,1024]
    const float* b1 = (const float*)d_in[2];  // [256]
    const float* w2 = (const float*)d_in[3];  // [64,256]
    const float* b2 = (const float*)d_in[4];  // [64]
    float* out = (float*)d_out;               // 131072 floats: idx then gates
    float* w1t = (float*)d_ws;                // W1T [1024][256], 1 MB

    transpose_w1<<<dim3(32, 8), 256, 0, stream>>>(w1, w1t);
    moe_gate<<<N_TOK / 32, 128, 0, stream>>>(x, w1t, b1, w2, b2, out);
}